// Round 1
// baseline (325.117 us; speedup 1.0000x reference)
//
#include <hip/hip_runtime.h>
#include <stdint.h>
#include <math.h>

// PendulumHJBLoss: 3 MLP passes (2->128->128->2, tanh) over N=524288 + losses.
// Hidden 128x128 matmul in bf16 MFMA (16x16x32); layers 1/3 + tanh in fp32.
// Symplectic finite-difference term computed exactly in fp32 (separate kernel,
// 128 rows only) because EPS=1e-4 differences cannot survive bf16 rounding.

constexpr float EPS_FD = 1e-4f;

typedef float f32x4 __attribute__((ext_vector_type(4)));
typedef short s16x8 __attribute__((ext_vector_type(8)));

__device__ __forceinline__ float tanh_fast(float x) {
  // tanh(x) = 1 - 2/(e^{2x}+1); exp2/rcp are single HW instrs.
  float e = __builtin_amdgcn_exp2f(x * 2.8853900817779268f); // 2*log2(e)
  return 1.0f - 2.0f * __builtin_amdgcn_rcpf(e + 1.0f);
}

__device__ __forceinline__ unsigned bf16rne(float f) {
  union { float f; unsigned u; } v; v.f = f;
  return (v.u + 0x7FFFu + ((v.u >> 16) & 1u)) >> 16;
}
__device__ __forceinline__ unsigned pack2(float a, float b) {
  return bf16rne(a) | (bf16rne(b) << 16);
}

// ---------------------------------------------------------------------------
// Pre-swizzle W2 (fp32 row-major [128][128]) into MFMA B-frag order, bf16.
// Frag f = s*8+t (s = k-step of 32, t = 16-col tile). Lane L holds
// B[k = 32s + (L>>4)*8 + j][col = 16t + (L&15)], j=0..7 packed as 4 u32.
// enc at frag[0..8191], dec at frag[8192..16383].
// ---------------------------------------------------------------------------
__global__ void prep_w2(const float* __restrict__ encW2,
                        const float* __restrict__ decW2,
                        unsigned* __restrict__ frag) {
  int id = blockIdx.x * blockDim.x + threadIdx.x;  // 0..16383
  const float* W = (id < 8192) ? encW2 : decW2;
  int l = id & 8191;
  int jj   = l & 3;
  int lane = (l >> 2) & 63;
  int f    = l >> 8;            // 0..31
  int s = f >> 3, t = f & 7;
  int quad = lane >> 4, nn = lane & 15;
  int k   = 32 * s + quad * 8 + 2 * jj;
  int col = 16 * t + nn;
  float v0 = W[k * 128 + col];
  float v1 = W[(k + 1) * 128 + col];
  frag[id] = pack2(v0, v1);
}

// ---------------------------------------------------------------------------
// One MLP pass: out[P,Q] = MLP(xp,xq). Per wave: 16-element tile.
// ---------------------------------------------------------------------------
__global__ __launch_bounds__(256) void mlp16(
    const float* __restrict__ xp, const float* __restrict__ xq,
    const uint4* __restrict__ w2frag,
    const float* __restrict__ W1, const float* __restrict__ b1,
    const float* __restrict__ b2,
    const float* __restrict__ W3, const float* __restrict__ b3,
    float* __restrict__ outP, float* __restrict__ outQ, int n)
{
  __shared__ uint4 Bf[2048];                 // 32 KB: all 32 B-frags
  __shared__ unsigned h1s[4][16 * 68 + 4];   // per-wave h1 staging, padded rows

  int tid = threadIdx.x;
  for (int i = tid; i < 2048; i += 256) Bf[i] = w2frag[i];

  int wave = tid >> 6, lane = tid & 63;
  int quad = lane >> 4, l15 = lane & 15;

  // loop-invariant per-lane constants
  float w10_0 = W1[2 * lane],     w10_1 = W1[2 * lane + 1];
  float w11_0 = W1[128 + 2 * lane], w11_1 = W1[128 + 2 * lane + 1];
  float b1_0 = b1[2 * lane], b1_1 = b1[2 * lane + 1];
  float b2v[8], w3P[8], w3Q[8];
#pragma unroll
  for (int t = 0; t < 8; t++) {
    b2v[t] = b2[16 * t + l15];
    w3P[t] = W3[(16 * t + l15) * 2];
    w3Q[t] = W3[(16 * t + l15) * 2 + 1];
  }
  float b3P = b3[0], b3Q = b3[1];
  __syncthreads();

  int nwaves = gridDim.x * 4;
  int gwave  = blockIdx.x * 4 + wave;
  int ntiles = (n + 15) >> 4;
  int iters  = (ntiles + nwaves - 1) / nwaves;
  unsigned* hrow = &h1s[wave][0];

  for (int it = 0; it < iters; it++) {
    int tile = gwave + it * nwaves;
    bool valid = tile < ntiles;
    int base = tile * 16;
    int eidx = base + l15; if (eidx >= n) eidx = n - 1;
    float pe = 0.f, qe = 0.f;
    if (valid) { pe = xp[eidx]; qe = xq[eidx]; }

    // layer 1: lane computes h1[e][2*lane], h1[e][2*lane+1] for e=0..15
#pragma unroll
    for (int e = 0; e < 16; e++) {
      float p = __shfl(pe, e, 64);
      float q = __shfl(qe, e, 64);
      float a0 = tanh_fast(fmaf(p, w10_0, fmaf(q, w11_0, b1_0)));
      float a1 = tanh_fast(fmaf(p, w10_1, fmaf(q, w11_1, b1_1)));
      hrow[e * 68 + lane] = pack2(a0, a1);
    }
    __syncthreads();

    // A-frags: lane L holds h1[e=L&15][k = 32s + quad*8 + j]
    s16x8 A[4];
#pragma unroll
    for (int s = 0; s < 4; s++) {
      uint4 u = *reinterpret_cast<const uint4*>(&hrow[l15 * 68 + 16 * s + 4 * quad]);
      A[s] = *reinterpret_cast<s16x8*>(&u);
    }

    f32x4 acc[8];
#pragma unroll
    for (int t = 0; t < 8; t++) { f32x4 z = {0.f, 0.f, 0.f, 0.f}; acc[t] = z; }
#pragma unroll
    for (int s = 0; s < 4; s++) {
#pragma unroll
      for (int t = 0; t < 8; t++) {
        uint4 bu = Bf[(s * 8 + t) * 64 + lane];
        s16x8 Bv = *reinterpret_cast<s16x8*>(&bu);
        acc[t] = __builtin_amdgcn_mfma_f32_16x16x32_bf16(A[s], Bv, acc[t], 0, 0, 0);
      }
    }

    // epilogue: acc[t][r] = pre-act h2 of element (quad*4+r), col (16t+l15)
    float sP[4] = {0, 0, 0, 0}, sQ[4] = {0, 0, 0, 0};
#pragma unroll
    for (int t = 0; t < 8; t++) {
#pragma unroll
      for (int r = 0; r < 4; r++) {
        float h = tanh_fast(acc[t][r] + b2v[t]);
        sP[r] = fmaf(h, w3P[t], sP[r]);
        sQ[r] = fmaf(h, w3Q[t], sQ[r]);
      }
    }
    // reduce layer-3 partials across the 16 lanes of each quad
#pragma unroll
    for (int m = 1; m < 16; m <<= 1) {
#pragma unroll
      for (int r = 0; r < 4; r++) {
        sP[r] += __shfl_xor(sP[r], m, 64);
        sQ[r] += __shfl_xor(sQ[r], m, 64);
      }
    }
    if (valid && l15 < 4) {
      float vP = (l15 == 0) ? sP[0] : (l15 == 1) ? sP[1] : (l15 == 2) ? sP[2] : sP[3];
      float vQ = (l15 == 0) ? sQ[0] : (l15 == 1) ? sQ[1] : (l15 == 2) ? sQ[2] : sQ[3];
      int o = base + quad * 4 + l15;
      if (o < n) { outP[o] = vP + b3P; outQ[o] = vQ + b3Q; }
    }
    __syncthreads();  // protect h1s before next iteration's writes
  }
}

// ---------------------------------------------------------------------------
// Elementwise losses -> 5 global accumulators (recon, cons, evo, gaugeP, gaugeQ)
// ---------------------------------------------------------------------------
__global__ void loss_kernel(const float* __restrict__ p0, const float* __restrict__ q0,
                            const float* __restrict__ omega, const float* __restrict__ dtp,
                            const float* __restrict__ Pt, const float* __restrict__ Qt,
                            const float* __restrict__ P0, const float* __restrict__ Q0,
                            const float* __restrict__ P1, const float* __restrict__ Q1,
                            const float* __restrict__ R0, const float* __restrict__ R1,
                            float* __restrict__ acc, int n)
{
  float dt = dtp[0];
  float s0 = 0.f, s1 = 0.f, s2 = 0.f, s3 = 0.f, s4 = 0.f;
  for (int i = blockIdx.x * blockDim.x + threadIdx.x; i < n;
       i += gridDim.x * blockDim.x) {
    float dp = p0[i] - R0[i], dq = q0[i] - R1[i];
    s0 += dp * dp + dq * dq;
    float dc = P0[i] - P1[i];
    s1 += dc * dc;
    s2 += 1.0f - cosf(Q1[i] - Q0[i] - omega[i] * dt);
    float gp = P0[i] - Pt[i];
    s3 += gp * gp;
    s4 += 1.0f - cosf(Q0[i] - Qt[i]);
  }
#pragma unroll
  for (int m = 1; m < 64; m <<= 1) {
    s0 += __shfl_xor(s0, m, 64);
    s1 += __shfl_xor(s1, m, 64);
    s2 += __shfl_xor(s2, m, 64);
    s3 += __shfl_xor(s3, m, 64);
    s4 += __shfl_xor(s4, m, 64);
  }
  __shared__ float red[4][5];
  int lane = threadIdx.x & 63, wave = threadIdx.x >> 6;
  if (lane == 0) {
    red[wave][0] = s0; red[wave][1] = s1; red[wave][2] = s2;
    red[wave][3] = s3; red[wave][4] = s4;
  }
  __syncthreads();
  if (threadIdx.x < 5) {
    float v = red[0][threadIdx.x] + red[1][threadIdx.x] +
              red[2][threadIdx.x] + red[3][threadIdx.x];
    atomicAdd(&acc[threadIdx.x], v);
  }
}

// ---------------------------------------------------------------------------
// Exact fp32 encode of the 128 perturbed symplectic rows (block = one row).
// ---------------------------------------------------------------------------
__global__ void symp_encode(const float* __restrict__ p0, const float* __restrict__ q0,
                            const float* __restrict__ W1, const float* __restrict__ b1,
                            const float* __restrict__ W2, const float* __restrict__ b2,
                            const float* __restrict__ W3, const float* __restrict__ b3,
                            float* __restrict__ PQ)
{
  int b = blockIdx.x;   // 0..127
  int t = threadIdx.x;  // 0..127
  int m = b & 31, c = b >> 5;   // c: 0=p+e 1=p-e 2=q+e 3=q-e
  float p = p0[m], q = q0[m];
  if (c == 0) p += EPS_FD; else if (c == 1) p -= EPS_FD;
  else if (c == 2) q += EPS_FD; else q -= EPS_FD;

  __shared__ float h1[128], h2[128];
  h1[t] = tanhf(fmaf(p, W1[t], fmaf(q, W1[128 + t], b1[t])));
  __syncthreads();
  float a = b2[t];
  for (int k = 0; k < 128; k++) a = fmaf(h1[k], W2[k * 128 + t], a);
  h2[t] = tanhf(a);
  __syncthreads();
  float cP = h2[t] * W3[2 * t];
  float cQ = h2[t] * W3[2 * t + 1];
#pragma unroll
  for (int mm = 1; mm < 64; mm <<= 1) {
    cP += __shfl_xor(cP, mm, 64);
    cQ += __shfl_xor(cQ, mm, 64);
  }
  __shared__ float rr[2][2];
  if ((t & 63) == 0) { rr[t >> 6][0] = cP; rr[t >> 6][1] = cQ; }
  __syncthreads();
  if (t == 0) {
    PQ[2 * b]     = rr[0][0] + rr[1][0] + b3[0];
    PQ[2 * b + 1] = rr[0][1] + rr[1][1] + b3[1];
  }
}

// ---------------------------------------------------------------------------
// Finite differences + Poisson bracket + weighted total -> d_out[6]
// ---------------------------------------------------------------------------
__global__ void finalize(const float* __restrict__ acc, const float* __restrict__ PQ,
                         float* __restrict__ out, int n)
{
  int t = threadIdx.x;  // 64 threads, 1 wave
  float v = 0.f;
  if (t < 32) {
    float Ppp = PQ[2 * t],            Qpp = PQ[2 * t + 1];
    float Ppm = PQ[2 * (32 + t)],     Qpm = PQ[2 * (32 + t) + 1];
    float Pqp = PQ[2 * (64 + t)],     Qqp = PQ[2 * (64 + t) + 1];
    float Pqm = PQ[2 * (96 + t)],     Qqm = PQ[2 * (96 + t) + 1];
    float inv2e = 1.0f / (2.0f * EPS_FD);
    float dPdp = (Ppp - Ppm) * inv2e, dPdq = (Pqp - Pqm) * inv2e;
    float dQdp = (Qpp - Qpm) * inv2e, dQdq = (Qqp - Qqm) * inv2e;
    float pb = dPdq * dQdp - dPdp * dQdq;
    float d = fabsf(pb) - 1.0f;
    v = d * d;
  }
#pragma unroll
  for (int m = 1; m < 64; m <<= 1) v += __shfl_xor(v, m, 64);
  if (t == 0) {
    float inv_n = 1.0f / (float)n;
    float recon = acc[0] * inv_n;
    float cons  = acc[1] * inv_n;
    float evo   = acc[2] * inv_n;
    float gauge = acc[3] * inv_n + acc[4] * inv_n;
    float symp  = v * (1.0f / 32.0f);
    float total = recon + 10.0f * cons + 5.0f * evo + 0.1f * symp + 5.0f * gauge;
    out[0] = total; out[1] = recon; out[2] = cons;
    out[3] = evo;   out[4] = symp;  out[5] = gauge;
  }
}

extern "C" void kernel_launch(void* const* d_in, const int* in_sizes, int n_in,
                              void* d_out, int out_size, void* d_ws, size_t ws_size,
                              hipStream_t stream)
{
  const float* p0    = (const float*)d_in[0];
  const float* q0    = (const float*)d_in[1];
  const float* p1    = (const float*)d_in[2];
  const float* q1    = (const float*)d_in[3];
  const float* omega = (const float*)d_in[4];
  const float* dtp   = (const float*)d_in[5];
  const float* Pt    = (const float*)d_in[6];
  const float* Qt    = (const float*)d_in[7];
  const float* encW1 = (const float*)d_in[8];
  const float* encb1 = (const float*)d_in[9];
  const float* encW2 = (const float*)d_in[10];
  const float* encb2 = (const float*)d_in[11];
  const float* encW3 = (const float*)d_in[12];
  const float* encb3 = (const float*)d_in[13];
  const float* decW1 = (const float*)d_in[14];
  const float* decb1 = (const float*)d_in[15];
  const float* decW2 = (const float*)d_in[16];
  const float* decb2 = (const float*)d_in[17];
  const float* decW3 = (const float*)d_in[18];
  const float* decb3 = (const float*)d_in[19];

  int n = in_sizes[0];
  char* ws = (char*)d_ws;
  unsigned* frag = (unsigned*)ws;              // enc: 8192 u32, dec: next 8192 (64 KB)
  float* P0 = (float*)(ws + 65536);
  float* Q0 = P0 + n;
  float* P1 = Q0 + n;
  float* Q1 = P1 + n;
  float* R0 = Q1 + n;
  float* R1 = R0 + n;
  float* acc = R1 + n;                          // 5 accumulators
  float* PQ  = acc + 8;                         // 256 floats (symp encodes)

  hipMemsetAsync(acc, 0, 5 * sizeof(float), stream);
  prep_w2<<<64, 256, 0, stream>>>(encW2, decW2, frag);

  mlp16<<<1024, 256, 0, stream>>>(p0, q0, (const uint4*)frag,
                                  encW1, encb1, encb2, encW3, encb3, P0, Q0, n);
  mlp16<<<1024, 256, 0, stream>>>(p1, q1, (const uint4*)frag,
                                  encW1, encb1, encb2, encW3, encb3, P1, Q1, n);
  mlp16<<<1024, 256, 0, stream>>>(P0, Q0, (const uint4*)(frag + 8192),
                                  decW1, decb1, decb2, decW3, decb3, R0, R1, n);

  symp_encode<<<128, 128, 0, stream>>>(p0, q0, encW1, encb1, encW2, encb2,
                                       encW3, encb3, PQ);
  loss_kernel<<<1024, 256, 0, stream>>>(p0, q0, omega, dtp, Pt, Qt,
                                        P0, Q0, P1, Q1, R0, R1, acc, n);
  finalize<<<1, 64, 0, stream>>>(acc, PQ, (float*)d_out, n);
}